// Round 10
// baseline (495.661 us; speedup 1.0000x reference)
//
#include <hip/hip_runtime.h>
#include <hip/hip_bf16.h>
#include <hip/hip_fp16.h>

typedef __hip_bfloat16 bf16;
typedef _Float16 half8 __attribute__((ext_vector_type(8)));
typedef float f32x4 __attribute__((ext_vector_type(4)));

#define FDIM 128
#define SELF_W 2.0f
#define NGRAPH 64
#define DEG_SCALE 1048576.0f          // 2^20 fixed point for weighted degree
#define DEG_MASK  ((1ull<<44) - 1ull) // low 44 bits = degree sum, high 20 = count

__device__ __forceinline__ float b2f(bf16 v){ return __bfloat162float(v); }

__device__ __forceinline__ float rdf(const void* p, long long i, int f32){
  return f32 ? ((const float*)p)[i] : b2f(((const bf16*)p)[i]);
}
__device__ __forceinline__ int rdi(const void* p, long long i, int i64){
  return i64 ? (int)(((const long long*)p)[i]) : ((const int*)p)[i];
}

// fast tanh: exp+rcp (~8 VALU vs ~30 for libm tanhf); rel err ~2e-7
__device__ __forceinline__ float tanh_fast(float x){
  float ax = fabsf(x);
  float e  = __expf(-2.0f*ax);
  float r  = (1.0f - e) * __builtin_amdgcn_rcpf(1.0f + e);
  return copysignf(r, x);
}

// ---- input-format probe: flags[0]=floats are f32, flags[1]=ints are int64 ----
__global__ __launch_bounds__(256) void k_probe(const unsigned short* __restrict__ x16,
                                               const int* __restrict__ ei32,
                                               int* __restrict__ flags){
  __shared__ int cbig, codd;
  int tid = threadIdx.x;
  if (tid == 0){ cbig = 0; codd = 0; }
  __syncthreads();
  for (int i = tid; i < 4096; i += 256){
    int e = (x16[i] >> 7) & 0xFF;
    if (e >= 134) atomicAdd(&cbig, 1);
  }
  for (int i = tid; i < 512; i += 256){
    if (ei32[2*i + 1] != 0) atomicAdd(&codd, 1);
  }
  __syncthreads();
  if (tid == 0){
    flags[0] = (cbig >= 64) ? 1 : 0;
    flags[1] = (codd < 8)  ? 1 : 0;
  }
}

// fused setup: params -> pf(f32) + WT(fp16,T); packed init; graph bounds (tail block)
struct PtrPack { const void* p[10]; };
__global__ __launch_bounds__(256) void k_setup(PtrPack pk, float* __restrict__ pf,
                                               _Float16* __restrict__ wt,
                                               unsigned long long* __restrict__ packed,
                                               const void* __restrict__ bat,
                                               unsigned* __restrict__ gstart,
                                               int N, const int* __restrict__ flags){
  const int sz[10]  = {16384,16384,16384,16384,128,128,128,128,256,1};
  const int dst[10] = {0,16384,32768,49152,65536,65664,65792,65920,66048,66304};
  int i = blockIdx.x*blockDim.x + threadIdx.x;
  if (i < 66305){
    int seg = 0, rem = i;
    while (rem >= sz[seg]){ rem -= sz[seg]; seg++; }
    float v = rdf(pk.p[seg], rem, flags[0]);
    pf[dst[seg] + rem] = v;
    if (seg < 4){                     // W[l][k][n] -> WT[l][n][k] fp16
      int k = rem >> 7, n = rem & 127;
      wt[seg*16384 + n*128 + k] = (_Float16)v;
    }
  }
  // packed degree init (grid-stride)
  int stride = gridDim.x*blockDim.x;
  for (int j = i; j < N; j += stride)
    packed[j] = (unsigned long long)(SELF_W * DEG_SCALE);
  // graph bounds in last block (batch is sorted)
  if (blockIdx.x == gridDim.x - 1){
    __shared__ unsigned s[NGRAPH+1];
    int g = threadIdx.x;
    int i64 = flags[1];
    if (g <= NGRAPH){
      int lo = 0, hi = N;
      while (lo < hi){ int mid = (lo + hi) >> 1; if (rdi(bat, mid, i64) < g) lo = mid + 1; else hi = mid; }
      s[g] = (unsigned)lo;
    }
    __syncthreads();
    if (g <= NGRAPH) gstart[g] = s[g];
  }
}

// edge pass 1: single u64 atomic = {count:20 | deg_fixed:44}; returned old
// value gives this edge's rank inside its dst bucket.
__global__ void k_edge_deg(const void* __restrict__ ei, const void* __restrict__ ew,
                           unsigned long long* __restrict__ packed,
                           unsigned* __restrict__ rank,
                           int E, int N, const int* __restrict__ flags){
  int e = blockIdx.x*blockDim.x + threadIdx.x;
  if (e >= E) return;
  int d = rdi(ei, (long long)E + e, flags[1]);
  unsigned r = 0u;
  if ((unsigned)d < (unsigned)N){
    float w = rdf(ew, e, flags[0]);
    unsigned long long add = (1ull << 44) |
        (unsigned long long)__float2uint_rn(w * DEG_SCALE);
    unsigned long long old = atomicAdd(&packed[d], add);
    r = (unsigned)(old >> 44);
  }
  rank[e] = r;
}

__device__ __forceinline__ unsigned wave_incl_scan(unsigned v){
  int lane = threadIdx.x & 63;
  #pragma unroll
  for (int d = 1; d < 64; d <<= 1){
    unsigned t = __shfl_up(v, d, 64);
    if (lane >= d) v += t;
  }
  return v;
}

// scan phase A: per-block PADDED-count sum -> bsum; fused dinv + self-weight;
// also prefills epk (grid-stride) before k_bucket's scatter.
__global__ __launch_bounds__(256) void k_scan_pre(const unsigned long long* __restrict__ packed,
                                                  float* __restrict__ dinv,
                                                  float* __restrict__ swv,
                                                  unsigned* __restrict__ bsum,
                                                  unsigned* __restrict__ epk, unsigned Epad,
                                                  int N){
  __shared__ unsigned wsh[4];
  int tid = threadIdx.x, lane = tid & 63, wid = tid >> 6;
  unsigned gid = blockIdx.x*blockDim.x + tid, gstr = gridDim.x*blockDim.x;
  for (unsigned j = gid; j < Epad; j += gstr) epk[j] = 0u;
  int i0 = blockIdx.x*1024 + tid*4;
  unsigned tsum = 0u;
  #pragma unroll
  for (int j = 0; j < 4; j++){
    int i = i0 + j;
    if (i < N){
      unsigned long long pv = packed[i];
      tsum += ((unsigned)(pv >> 44) + 7u) & ~7u;
      float d = (float)(pv & DEG_MASK) * (1.0f / DEG_SCALE);
      float di = (d > 0.f) ? rsqrtf(d) : 0.f;
      dinv[i] = di;
      swv[i]  = di * di * SELF_W;
    }
  }
  #pragma unroll
  for (int d = 1; d < 64; d <<= 1) tsum += __shfl_down(tsum, d, 64);
  if (lane == 0) wsh[wid] = tsum;
  __syncthreads();
  if (tid == 0) bsum[blockIdx.x] = wsh[0] + wsh[1] + wsh[2] + wsh[3];
}

// scan phase B: one wave scans block sums (nb <= 64) -> exclusive base; off[N]=total
__global__ __launch_bounds__(64) void k_scan_mid(unsigned* __restrict__ bsum,
                                                 unsigned* __restrict__ off,
                                                 int nb, int N){
  int lane = threadIdx.x;
  unsigned v = (lane < nb) ? bsum[lane] : 0u;
  unsigned isc = wave_incl_scan(v);
  if (lane < nb) bsum[lane] = isc - v;
  if (lane == 63) off[N] = isc;
}

// scan phase C: per-block local exclusive scan of padded counts + base -> off
__global__ __launch_bounds__(256) void k_scan_fin(const unsigned long long* __restrict__ packed,
                                                  const unsigned* __restrict__ bsum,
                                                  unsigned* __restrict__ off, int N){
  __shared__ unsigned wsh[4];
  int tid = threadIdx.x, lane = tid & 63, wid = tid >> 6;
  int i0 = blockIdx.x*1024 + tid*4;
  unsigned v0=0u,v1=0u,v2=0u,v3=0u;
  if (i0+0 < N) v0 = ((unsigned)(packed[i0+0] >> 44) + 7u) & ~7u;
  if (i0+1 < N) v1 = ((unsigned)(packed[i0+1] >> 44) + 7u) & ~7u;
  if (i0+2 < N) v2 = ((unsigned)(packed[i0+2] >> 44) + 7u) & ~7u;
  if (i0+3 < N) v3 = ((unsigned)(packed[i0+3] >> 44) + 7u) & ~7u;
  unsigned tsum = v0+v1+v2+v3;
  unsigned isc = wave_incl_scan(tsum);
  if (lane == 63) wsh[wid] = isc;
  __syncthreads();
  unsigned wbase = 0u;
  #pragma unroll
  for (int w = 0; w < 4; w++) if (w < wid) wbase += wsh[w];
  unsigned ex = bsum[blockIdx.x] + wbase + (isc - tsum);
  if (i0+0 < N) off[i0+0] = ex;
  if (i0+1 < N) off[i0+1] = ex + v0;
  if (i0+2 < N) off[i0+2] = ex + v0 + v1;
  if (i0+3 < N) off[i0+3] = ex + v0 + v1 + v2;
}

// edge pass 2: ATOMIC-FREE scatter; pack (u16 src | fp16 coef) into u32
__global__ void k_bucket(const void* __restrict__ ei, const void* __restrict__ ew,
                         const float* __restrict__ dinv,
                         const unsigned* __restrict__ off,
                         const unsigned* __restrict__ rank,
                         unsigned* __restrict__ epk,
                         int E, unsigned Epad, int N, const int* __restrict__ flags){
  int e = blockIdx.x*blockDim.x + threadIdx.x;
  if (e >= E) return;
  int s_ = rdi(ei, e, flags[1]);
  int d  = rdi(ei, (long long)E + e, flags[1]);
  if ((unsigned)s_ >= (unsigned)N || (unsigned)d >= (unsigned)N) return;
  unsigned pos = off[d] + rank[e];
  if (pos < Epad){
    float coef = dinv[s_] * rdf(ew, e, flags[0]) * dinv[d];
    _Float16 ch = (_Float16)coef;
    unsigned cu = (unsigned)__builtin_bit_cast(unsigned short, ch);
    epk[pos] = ((unsigned)s_ & 0xffffu) | (cu << 16);
  }
}

// MFMA GEMM: t(panels) = in[N,128] @ W; fp16 PANEL-layout output [4][N*32].
// MODE 0: in = raw x dense (flag-aware). MODE 1: in = fp16 panels.
template<int MODE>
__global__ __launch_bounds__(256) void k_gemm(const void* __restrict__ in,
                                              const _Float16* __restrict__ WT,
                                              _Float16* __restrict__ outp, int N,
                                              size_t pstride,
                                              const int* __restrict__ flags){
  __shared__ _Float16 sout[4*16*136];   // [wave][16 rows][128+8 cols]
  int tid  = threadIdx.x;
  int wid  = tid >> 6, lane = tid & 63;
  int ln   = lane & 15, quad = lane >> 4;
  int row0 = blockIdx.x * 64;
  int rowA = row0 + wid*16 + ln;
  int rA   = (rowA < N) ? rowA : (N > 0 ? N-1 : 0);

  half8 af[4];
  if (MODE == 1){
    const _Float16* src = (const _Float16*)in;
    #pragma unroll
    for (int kc = 0; kc < 4; kc++)
      af[kc] = *(const half8*)(src + (size_t)kc*pstride + (size_t)rA*32 + quad*8);
  } else {
    if (flags[0]){
      const float* src = (const float*)in + (size_t)rA*FDIM + quad*8;
      #pragma unroll
      for (int kc = 0; kc < 4; kc++){
        float4 a = *(const float4*)(src + kc*32);
        float4 b = *(const float4*)(src + kc*32 + 4);
        half8 h; h[0]=(_Float16)a.x; h[1]=(_Float16)a.y; h[2]=(_Float16)a.z; h[3]=(_Float16)a.w;
        h[4]=(_Float16)b.x; h[5]=(_Float16)b.y; h[6]=(_Float16)b.z; h[7]=(_Float16)b.w;
        af[kc] = h;
      }
    } else {
      const unsigned short* src = (const unsigned short*)in + (size_t)rA*FDIM + quad*8;
      #pragma unroll
      for (int kc = 0; kc < 4; kc++){
        ushort4 u0 = *(const ushort4*)(src + kc*32);
        ushort4 u1 = *(const ushort4*)(src + kc*32 + 4);
        half8 h;
        h[0]=(_Float16)__uint_as_float((unsigned)u0.x<<16);
        h[1]=(_Float16)__uint_as_float((unsigned)u0.y<<16);
        h[2]=(_Float16)__uint_as_float((unsigned)u0.z<<16);
        h[3]=(_Float16)__uint_as_float((unsigned)u0.w<<16);
        h[4]=(_Float16)__uint_as_float((unsigned)u1.x<<16);
        h[5]=(_Float16)__uint_as_float((unsigned)u1.y<<16);
        h[6]=(_Float16)__uint_as_float((unsigned)u1.z<<16);
        h[7]=(_Float16)__uint_as_float((unsigned)u1.w<<16);
        af[kc] = h;
      }
    }
  }

  f32x4 acc[8];
  #pragma unroll
  for (int nt = 0; nt < 8; nt++) acc[nt] = (f32x4){0.f,0.f,0.f,0.f};

  #pragma unroll
  for (int kc = 0; kc < 4; kc++){
    #pragma unroll
    for (int nt = 0; nt < 8; nt++){
      half8 bf = *(const half8*)(WT + (size_t)(nt*16 + ln)*FDIM + kc*32 + quad*8);
      acc[nt] = __builtin_amdgcn_mfma_f32_16x16x32_f16(af[kc], bf, acc[nt], 0, 0, 0);
    }
  }

  _Float16* so = sout + wid*2176;
  #pragma unroll
  for (int nt = 0; nt < 8; nt++)
    #pragma unroll
    for (int reg = 0; reg < 4; reg++)
      so[(quad*4 + reg)*136 + nt*16 + ln] = (_Float16)acc[nt][reg];
  __syncthreads();

  #pragma unroll
  for (int c = 0; c < 4; c++){
    int chunk = tid + c*256;
    int r = chunk >> 4, co = (chunk & 15)*8;
    int row = row0 + r;
    if (row < N){
      half8 v = *(const half8*)(sout + (r>>4)*2176 + (r&15)*136 + co);
      *(half8*)(outp + (size_t)(co>>5)*pstride + (size_t)row*32 + (co & 31)) = v;
    }
  }
}

// panel aggregation: wave = 4 nodes x 1 panel; QUAD = NODE. 16 lanes own one
// half2 column each; walk padded edge list (x8, no tail), 8-edge unrolled.
// Edge = u32 (u16 src | fp16 coef), 8 edges = two uint4. panel = blockIdx&3.
__global__ __launch_bounds__(256) void k_agg(const _Float16* __restrict__ tp,
                                             const float* __restrict__ swv,
                                             const unsigned* __restrict__ off,
                                             const unsigned* __restrict__ epk,
                                             const float* __restrict__ bias,
                                             _Float16* __restrict__ hp,
                                             int N, size_t pstride){
  int tid  = threadIdx.x;
  int wv   = tid >> 6, lane = tid & 63;
  int quad = lane >> 4, ql = lane & 15;
  int panel = blockIdx.x & 3;
  int n = (blockIdx.x >> 2)*16 + wv*4 + quad;
  bool valid = (n < N);
  int nn = valid ? n : 0;
  const _Float16* tpp = tp + (size_t)panel*pstride;
  const _Float16* myt = tpp + ql*2;

  float sw = swv[nn];
  float2 sv = __half22float2(*(const __half2*)(myt + (size_t)nn*32));
  float a0 = sw * sv.x, a1 = sw * sv.y;
  float b0 = 0.f, b1 = 0.f;

  unsigned beg = off[nn];
  unsigned end = valid ? off[nn+1] : beg;
  for (unsigned i = beg; i < end; i += 8){
    uint4 p0 = *(const uint4*)(epk + i);
    uint4 p1 = *(const uint4*)(epk + i + 4);
    unsigned vs[8] = {p0.x,p0.y,p0.z,p0.w,p1.x,p1.y,p1.z,p1.w};
    __half2 tv[8];
    #pragma unroll
    for (int j = 0; j < 8; j++)
      tv[j] = *(const __half2*)(myt + (size_t)(vs[j] & 0xffffu)*32);
    #pragma unroll
    for (int j = 0; j < 8; j++){
      float w = (float)__builtin_bit_cast(_Float16, (unsigned short)(vs[j] >> 16));
      float2 tf = __half22float2(tv[j]);
      if (j & 1){ b0 += w * tf.x; b1 += w * tf.y; }
      else      { a0 += w * tf.x; a1 += w * tf.y; }
    }
  }
  a0 += b0; a1 += b1;
  int cc = panel*32 + ql*2;
  a0 = tanh_fast(a0 + bias[cc]);
  a1 = tanh_fast(a1 + bias[cc+1]);
  if (valid)
    *(__half2*)(hp + (size_t)panel*pstride + (size_t)n*32 + ql*2) = __floats2half2_rn(a0, a1);
}

// fused pooling + head: 64 blocks (one per graph). Contiguous segment ->
// register max/sum (no atomics, no init), then hidden write + Wout dot.
__global__ __launch_bounds__(256) void k_pool_out(const _Float16* __restrict__ hp,
                                                  const unsigned* __restrict__ gstart,
                                                  const float* __restrict__ Wout,
                                                  const float* __restrict__ bout,
                                                  void* __restrict__ outp,
                                                  size_t pstride,
                                                  const int* __restrict__ flags){
  int g = blockIdx.x, tid = threadIdx.x;
  int col = tid & 127, sub = tid >> 7;      // 2 threads per column
  const _Float16* hpp = hp + (size_t)(col >> 5)*pstride + (col & 31);
  unsigned s0 = gstart[g], s1 = gstart[g+1];
  float m = -INFINITY, sm = 0.f;
  for (unsigned n = s0 + sub; n < s1; n += 2){
    float v = (float)hpp[(size_t)n*32];
    m = fmaxf(m, v); sm += v;
  }
  __shared__ float shm[256], shs[256];
  shm[tid] = m; shs[tid] = sm;
  __syncthreads();
  unsigned cnt = s1 - s0;
  float val;
  if (sub == 0){
    float mm = fmaxf(shm[tid], shm[tid + 128]);
    val = (cnt > 0 && mm > -INFINITY) ? mm : 0.f;   // empty-graph guard
  } else {
    float ss = shs[tid] + shs[tid - 128];
    val = ss / (float)(cnt ? cnt : 1u);
  }
  int hcol = (sub == 0) ? col : (128 + col);
  int f32out = flags[0];
  int hidx = NGRAPH + g*(2*FDIM) + hcol;
  if (f32out) ((float*)outp)[hidx] = val;
  else        ((bf16*)outp)[hidx] = __float2bfloat16(val);

  __shared__ float red[256];
  red[hcol] = val * Wout[hcol];
  __syncthreads();
  for (int s = 128; s > 0; s >>= 1){
    if (tid < s) red[tid] += red[tid + s];
    __syncthreads();
  }
  if (tid == 0){
    float o = red[0] + bout[0];
    if (f32out) ((float*)outp)[g] = o;
    else        ((bf16*)outp)[g] = __float2bfloat16(o);
  }
}

extern "C" void kernel_launch(void* const* d_in, const int* in_sizes, int n_in,
                              void* d_out, int out_size, void* d_ws, size_t ws_size,
                              hipStream_t stream){
  int N = in_sizes[0] / FDIM;   // x: [N,128]
  int E = in_sizes[3];          // edge_weight: [E]
  int NB = (N + 1023) / 1024;   // scan blocks (<=64 for N<=65536)
  unsigned Epad = (unsigned)E + 8u*(unsigned)N;   // allocation bound for padded CSR
  size_t pstride = (size_t)N * 32;                // fp16 elems per column panel

  char* p = (char*)d_ws;
  auto alloc = [&](size_t bytes){ char* r = p; p += (bytes + 255) & ~(size_t)255; return r; };
  int*       flags  = (int*)      alloc(16);
  float*     pf     = (float*)    alloc((size_t)(66305 + 64)*4);
  _Float16*  wt     = (_Float16*) alloc((size_t)4*FDIM*FDIM*2);
  unsigned long long* packed = (unsigned long long*)alloc((size_t)N*8);
  float*     dinv   = (float*)    alloc((size_t)N*4);
  float*     swv    = (float*)    alloc((size_t)N*4);
  unsigned*  off    = (unsigned*) alloc((size_t)(N+1)*4);
  unsigned*  bsum   = (unsigned*) alloc((size_t)128*4);
  unsigned*  rank   = (unsigned*) alloc((size_t)E*4);
  unsigned*  epk    = (unsigned*) alloc((size_t)Epad*4);
  _Float16*  th     = (_Float16*) alloc((size_t)N*FDIM*2);  // 4 panels
  _Float16*  hh     = (_Float16*) alloc((size_t)N*FDIM*2);  // 4 panels
  unsigned*  gstart = (unsigned*) alloc((size_t)(NGRAPH+1)*4);

  float* bf_[4] = {pf + 65536, pf + 65664, pf + 65792, pf + 65920};
  float* Woutf  = pf + 66048;
  float* boutf  = pf + 66304;

  k_probe<<<1, 256, 0, stream>>>((const unsigned short*)d_in[0], (const int*)d_in[1], flags);

  int gE = (E + 255)/256;
  PtrPack pk;
  pk.p[0]=d_in[4]; pk.p[1]=d_in[6]; pk.p[2]=d_in[8]; pk.p[3]=d_in[10];
  pk.p[4]=d_in[5]; pk.p[5]=d_in[7]; pk.p[6]=d_in[9]; pk.p[7]=d_in[11];
  pk.p[8]=d_in[12]; pk.p[9]=d_in[13];
  k_setup<<<(66305 + 255)/256, 256, 0, stream>>>(pk, pf, wt, packed, d_in[2], gstart, N, flags);
  k_edge_deg<<<gE, 256, 0, stream>>>(d_in[1], d_in[3], packed, rank, E, N, flags);
  k_scan_pre<<<NB, 256, 0, stream>>>(packed, dinv, swv, bsum, epk, Epad, N);
  k_scan_mid<<<1, 64, 0, stream>>>(bsum, off, NB, N);
  k_scan_fin<<<NB, 256, 0, stream>>>(packed, bsum, off, N);
  k_bucket<<<gE, 256, 0, stream>>>(d_in[1], d_in[3], dinv, off, rank, epk, E, Epad, N, flags);

  int gG = (N + 63)/64;
  int gA = ((N + 15)/16)*4;     // node-groups(16) x 4 panels

  k_gemm<0><<<gG, 256, 0, stream>>>(d_in[0], wt + 0*16384, th, N, pstride, flags);
  k_agg<<<gA, 256, 0, stream>>>(th, swv, off, epk, bf_[0], hh, N, pstride);
  for (int l = 1; l < 4; l++){
    k_gemm<1><<<gG, 256, 0, stream>>>(hh, wt + (size_t)l*16384, th, N, pstride, flags);
    k_agg<<<gA, 256, 0, stream>>>(th, swv, off, epk, bf_[l], hh, N, pstride);
  }

  k_pool_out<<<NGRAPH, 256, 0, stream>>>(hh, gstart, Woutf, boutf, d_out, pstride, flags);
}

// Round 11
// 376.458 us; speedup vs baseline: 1.3166x; 1.3166x over previous
//
#include <hip/hip_runtime.h>
#include <hip/hip_bf16.h>
#include <hip/hip_fp16.h>

typedef __hip_bfloat16 bf16;
typedef _Float16 half8 __attribute__((ext_vector_type(8)));
typedef float f32x4 __attribute__((ext_vector_type(4)));

#define FDIM 128
#define SELF_W 2.0f
#define NGRAPH 64
#define DEG_SCALE 1048576.0f          // 2^20 fixed point for weighted degree
#define DEG_MASK  ((1ull<<44) - 1ull) // low 44 bits = degree sum, high 20 = count

__device__ __forceinline__ float b2f(bf16 v){ return __bfloat162float(v); }

__device__ __forceinline__ float rdf(const void* p, long long i, int f32){
  return f32 ? ((const float*)p)[i] : b2f(((const bf16*)p)[i]);
}
__device__ __forceinline__ int rdi(const void* p, long long i, int i64){
  return i64 ? (int)(((const long long*)p)[i]) : ((const int*)p)[i];
}

// fast tanh: exp+rcp (~8 VALU vs ~30 for libm tanhf); rel err ~2e-7
__device__ __forceinline__ float tanh_fast(float x){
  float ax = fabsf(x);
  float e  = __expf(-2.0f*ax);
  float r  = (1.0f - e) * __builtin_amdgcn_rcpf(1.0f + e);
  return copysignf(r, x);
}

// ---- input-format probe: flags[0]=floats are f32, flags[1]=ints are int64 ----
__global__ __launch_bounds__(256) void k_probe(const unsigned short* __restrict__ x16,
                                               const int* __restrict__ ei32,
                                               int* __restrict__ flags){
  __shared__ int cbig, codd;
  int tid = threadIdx.x;
  if (tid == 0){ cbig = 0; codd = 0; }
  __syncthreads();
  for (int i = tid; i < 4096; i += 256){
    int e = (x16[i] >> 7) & 0xFF;
    if (e >= 134) atomicAdd(&cbig, 1);
  }
  for (int i = tid; i < 512; i += 256){
    if (ei32[2*i + 1] != 0) atomicAdd(&codd, 1);
  }
  __syncthreads();
  if (tid == 0){
    flags[0] = (cbig >= 64) ? 1 : 0;
    flags[1] = (codd < 8)  ? 1 : 0;
  }
}

// fused setup: params -> pf(f32) + WT(fp16,T); packed init; graph bounds (tail block)
struct PtrPack { const void* p[10]; };
__global__ __launch_bounds__(256) void k_setup(PtrPack pk, float* __restrict__ pf,
                                               _Float16* __restrict__ wt,
                                               unsigned long long* __restrict__ packed,
                                               const void* __restrict__ bat,
                                               unsigned* __restrict__ gstart,
                                               int N, const int* __restrict__ flags){
  const int sz[10]  = {16384,16384,16384,16384,128,128,128,128,256,1};
  const int dst[10] = {0,16384,32768,49152,65536,65664,65792,65920,66048,66304};
  int i = blockIdx.x*blockDim.x + threadIdx.x;
  if (i < 66305){
    int seg = 0, rem = i;
    while (rem >= sz[seg]){ rem -= sz[seg]; seg++; }
    float v = rdf(pk.p[seg], rem, flags[0]);
    pf[dst[seg] + rem] = v;
    if (seg < 4){                     // W[l][k][n] -> WT[l][n][k] fp16
      int k = rem >> 7, n = rem & 127;
      wt[seg*16384 + n*128 + k] = (_Float16)v;
    }
  }
  // packed degree init (grid-stride)
  int stride = gridDim.x*blockDim.x;
  for (int j = i; j < N; j += stride)
    packed[j] = (unsigned long long)(SELF_W * DEG_SCALE);
  // graph bounds in last block (batch is sorted)
  if (blockIdx.x == gridDim.x - 1){
    __shared__ unsigned s[NGRAPH+1];
    int g = threadIdx.x;
    int i64 = flags[1];
    if (g <= NGRAPH){
      int lo = 0, hi = N;
      while (lo < hi){ int mid = (lo + hi) >> 1; if (rdi(bat, mid, i64) < g) lo = mid + 1; else hi = mid; }
      s[g] = (unsigned)lo;
    }
    __syncthreads();
    if (g <= NGRAPH) gstart[g] = s[g];
  }
}

// edge pass 1: single u64 atomic = {count:20 | deg_fixed:44}; returned old
// value gives this edge's rank inside its dst bucket.
__global__ void k_edge_deg(const void* __restrict__ ei, const void* __restrict__ ew,
                           unsigned long long* __restrict__ packed,
                           unsigned* __restrict__ rank,
                           int E, int N, const int* __restrict__ flags){
  int e = blockIdx.x*blockDim.x + threadIdx.x;
  if (e >= E) return;
  int d = rdi(ei, (long long)E + e, flags[1]);
  unsigned r = 0u;
  if ((unsigned)d < (unsigned)N){
    float w = rdf(ew, e, flags[0]);
    unsigned long long add = (1ull << 44) |
        (unsigned long long)__float2uint_rn(w * DEG_SCALE);
    unsigned long long old = atomicAdd(&packed[d], add);
    r = (unsigned)(old >> 44);
  }
  rank[e] = r;
}

__device__ __forceinline__ unsigned wave_incl_scan(unsigned v){
  int lane = threadIdx.x & 63;
  #pragma unroll
  for (int d = 1; d < 64; d <<= 1){
    unsigned t = __shfl_up(v, d, 64);
    if (lane >= d) v += t;
  }
  return v;
}

// scan phase A: per-block PADDED-count sum -> bsum; fused dinv + self-weight;
// also prefills epk (grid-stride) before k_bucket's scatter.
__global__ __launch_bounds__(256) void k_scan_pre(const unsigned long long* __restrict__ packed,
                                                  float* __restrict__ dinv,
                                                  float* __restrict__ swv,
                                                  unsigned* __restrict__ bsum,
                                                  unsigned* __restrict__ epk, unsigned Epad,
                                                  int N){
  __shared__ unsigned wsh[4];
  int tid = threadIdx.x, lane = tid & 63, wid = tid >> 6;
  unsigned gid = blockIdx.x*blockDim.x + tid, gstr = gridDim.x*blockDim.x;
  for (unsigned j = gid; j < Epad; j += gstr) epk[j] = 0u;
  int i0 = blockIdx.x*1024 + tid*4;
  unsigned tsum = 0u;
  #pragma unroll
  for (int j = 0; j < 4; j++){
    int i = i0 + j;
    if (i < N){
      unsigned long long pv = packed[i];
      tsum += ((unsigned)(pv >> 44) + 7u) & ~7u;
      float d = (float)(pv & DEG_MASK) * (1.0f / DEG_SCALE);
      float di = (d > 0.f) ? rsqrtf(d) : 0.f;
      dinv[i] = di;
      swv[i]  = di * di * SELF_W;
    }
  }
  #pragma unroll
  for (int d = 1; d < 64; d <<= 1) tsum += __shfl_down(tsum, d, 64);
  if (lane == 0) wsh[wid] = tsum;
  __syncthreads();
  if (tid == 0) bsum[blockIdx.x] = wsh[0] + wsh[1] + wsh[2] + wsh[3];
}

// scan phase B: one wave scans block sums (nb <= 64) -> exclusive base; off[N]=total
__global__ __launch_bounds__(64) void k_scan_mid(unsigned* __restrict__ bsum,
                                                 unsigned* __restrict__ off,
                                                 int nb, int N){
  int lane = threadIdx.x;
  unsigned v = (lane < nb) ? bsum[lane] : 0u;
  unsigned isc = wave_incl_scan(v);
  if (lane < nb) bsum[lane] = isc - v;
  if (lane == 63) off[N] = isc;
}

// scan phase C: per-block local exclusive scan of padded counts + base -> off
__global__ __launch_bounds__(256) void k_scan_fin(const unsigned long long* __restrict__ packed,
                                                  const unsigned* __restrict__ bsum,
                                                  unsigned* __restrict__ off, int N){
  __shared__ unsigned wsh[4];
  int tid = threadIdx.x, lane = tid & 63, wid = tid >> 6;
  int i0 = blockIdx.x*1024 + tid*4;
  unsigned v0=0u,v1=0u,v2=0u,v3=0u;
  if (i0+0 < N) v0 = ((unsigned)(packed[i0+0] >> 44) + 7u) & ~7u;
  if (i0+1 < N) v1 = ((unsigned)(packed[i0+1] >> 44) + 7u) & ~7u;
  if (i0+2 < N) v2 = ((unsigned)(packed[i0+2] >> 44) + 7u) & ~7u;
  if (i0+3 < N) v3 = ((unsigned)(packed[i0+3] >> 44) + 7u) & ~7u;
  unsigned tsum = v0+v1+v2+v3;
  unsigned isc = wave_incl_scan(tsum);
  if (lane == 63) wsh[wid] = isc;
  __syncthreads();
  unsigned wbase = 0u;
  #pragma unroll
  for (int w = 0; w < 4; w++) if (w < wid) wbase += wsh[w];
  unsigned ex = bsum[blockIdx.x] + wbase + (isc - tsum);
  if (i0+0 < N) off[i0+0] = ex;
  if (i0+1 < N) off[i0+1] = ex + v0;
  if (i0+2 < N) off[i0+2] = ex + v0 + v1;
  if (i0+3 < N) off[i0+3] = ex + v0 + v1 + v2;
}

// edge pass 2: ATOMIC-FREE scatter; pack (u16 src | fp16 coef) into u32
__global__ void k_bucket(const void* __restrict__ ei, const void* __restrict__ ew,
                         const float* __restrict__ dinv,
                         const unsigned* __restrict__ off,
                         const unsigned* __restrict__ rank,
                         unsigned* __restrict__ epk,
                         int E, unsigned Epad, int N, const int* __restrict__ flags){
  int e = blockIdx.x*blockDim.x + threadIdx.x;
  if (e >= E) return;
  int s_ = rdi(ei, e, flags[1]);
  int d  = rdi(ei, (long long)E + e, flags[1]);
  if ((unsigned)s_ >= (unsigned)N || (unsigned)d >= (unsigned)N) return;
  unsigned pos = off[d] + rank[e];
  if (pos < Epad){
    float coef = dinv[s_] * rdf(ew, e, flags[0]) * dinv[d];
    _Float16 ch = (_Float16)coef;
    unsigned cu = (unsigned)__builtin_bit_cast(unsigned short, ch);
    epk[pos] = ((unsigned)s_ & 0xffffu) | (cu << 16);
  }
}

// MFMA GEMM: t(panels) = in[N,128] @ W; fp16 PANEL-layout output [4][N*32].
// MODE 0: in = raw x dense (flag-aware). MODE 1: in = fp16 panels.
template<int MODE>
__global__ __launch_bounds__(256) void k_gemm(const void* __restrict__ in,
                                              const _Float16* __restrict__ WT,
                                              _Float16* __restrict__ outp, int N,
                                              size_t pstride,
                                              const int* __restrict__ flags){
  __shared__ _Float16 sout[4*16*136];   // [wave][16 rows][128+8 cols]
  int tid  = threadIdx.x;
  int wid  = tid >> 6, lane = tid & 63;
  int ln   = lane & 15, quad = lane >> 4;
  int row0 = blockIdx.x * 64;
  int rowA = row0 + wid*16 + ln;
  int rA   = (rowA < N) ? rowA : (N > 0 ? N-1 : 0);

  half8 af[4];
  if (MODE == 1){
    const _Float16* src = (const _Float16*)in;
    #pragma unroll
    for (int kc = 0; kc < 4; kc++)
      af[kc] = *(const half8*)(src + (size_t)kc*pstride + (size_t)rA*32 + quad*8);
  } else {
    if (flags[0]){
      const float* src = (const float*)in + (size_t)rA*FDIM + quad*8;
      #pragma unroll
      for (int kc = 0; kc < 4; kc++){
        float4 a = *(const float4*)(src + kc*32);
        float4 b = *(const float4*)(src + kc*32 + 4);
        half8 h; h[0]=(_Float16)a.x; h[1]=(_Float16)a.y; h[2]=(_Float16)a.z; h[3]=(_Float16)a.w;
        h[4]=(_Float16)b.x; h[5]=(_Float16)b.y; h[6]=(_Float16)b.z; h[7]=(_Float16)b.w;
        af[kc] = h;
      }
    } else {
      const unsigned short* src = (const unsigned short*)in + (size_t)rA*FDIM + quad*8;
      #pragma unroll
      for (int kc = 0; kc < 4; kc++){
        ushort4 u0 = *(const ushort4*)(src + kc*32);
        ushort4 u1 = *(const ushort4*)(src + kc*32 + 4);
        half8 h;
        h[0]=(_Float16)__uint_as_float((unsigned)u0.x<<16);
        h[1]=(_Float16)__uint_as_float((unsigned)u0.y<<16);
        h[2]=(_Float16)__uint_as_float((unsigned)u0.z<<16);
        h[3]=(_Float16)__uint_as_float((unsigned)u0.w<<16);
        h[4]=(_Float16)__uint_as_float((unsigned)u1.x<<16);
        h[5]=(_Float16)__uint_as_float((unsigned)u1.y<<16);
        h[6]=(_Float16)__uint_as_float((unsigned)u1.z<<16);
        h[7]=(_Float16)__uint_as_float((unsigned)u1.w<<16);
        af[kc] = h;
      }
    }
  }

  f32x4 acc[8];
  #pragma unroll
  for (int nt = 0; nt < 8; nt++) acc[nt] = (f32x4){0.f,0.f,0.f,0.f};

  #pragma unroll
  for (int kc = 0; kc < 4; kc++){
    #pragma unroll
    for (int nt = 0; nt < 8; nt++){
      half8 bf = *(const half8*)(WT + (size_t)(nt*16 + ln)*FDIM + kc*32 + quad*8);
      acc[nt] = __builtin_amdgcn_mfma_f32_16x16x32_f16(af[kc], bf, acc[nt], 0, 0, 0);
    }
  }

  _Float16* so = sout + wid*2176;
  #pragma unroll
  for (int nt = 0; nt < 8; nt++)
    #pragma unroll
    for (int reg = 0; reg < 4; reg++)
      so[(quad*4 + reg)*136 + nt*16 + ln] = (_Float16)acc[nt][reg];
  __syncthreads();

  #pragma unroll
  for (int c = 0; c < 4; c++){
    int chunk = tid + c*256;
    int r = chunk >> 4, co = (chunk & 15)*8;
    int row = row0 + r;
    if (row < N){
      half8 v = *(const half8*)(sout + (r>>4)*2176 + (r&15)*136 + co);
      *(half8*)(outp + (size_t)(co>>5)*pstride + (size_t)row*32 + (co & 31)) = v;
    }
  }
}

// panel aggregation: wave = 4 nodes x 1 panel; QUAD = NODE. 16 lanes own one
// half2 column each; walk padded edge list (x8, no tail), 8-edge unrolled.
// Edge = u32 (u16 src | fp16 coef), 8 edges = two uint4. panel = blockIdx&3.
__global__ __launch_bounds__(256) void k_agg(const _Float16* __restrict__ tp,
                                             const float* __restrict__ swv,
                                             const unsigned* __restrict__ off,
                                             const unsigned* __restrict__ epk,
                                             const float* __restrict__ bias,
                                             _Float16* __restrict__ hp,
                                             int N, size_t pstride){
  int tid  = threadIdx.x;
  int wv   = tid >> 6, lane = tid & 63;
  int quad = lane >> 4, ql = lane & 15;
  int panel = blockIdx.x & 3;
  int n = (blockIdx.x >> 2)*16 + wv*4 + quad;
  bool valid = (n < N);
  int nn = valid ? n : 0;
  const _Float16* tpp = tp + (size_t)panel*pstride;
  const _Float16* myt = tpp + ql*2;

  float sw = swv[nn];
  float2 sv = __half22float2(*(const __half2*)(myt + (size_t)nn*32));
  float a0 = sw * sv.x, a1 = sw * sv.y;
  float b0 = 0.f, b1 = 0.f;

  unsigned beg = off[nn];
  unsigned end = valid ? off[nn+1] : beg;
  for (unsigned i = beg; i < end; i += 8){
    uint4 p0 = *(const uint4*)(epk + i);
    uint4 p1 = *(const uint4*)(epk + i + 4);
    unsigned vs[8] = {p0.x,p0.y,p0.z,p0.w,p1.x,p1.y,p1.z,p1.w};
    __half2 tv[8];
    #pragma unroll
    for (int j = 0; j < 8; j++)
      tv[j] = *(const __half2*)(myt + (size_t)(vs[j] & 0xffffu)*32);
    #pragma unroll
    for (int j = 0; j < 8; j++){
      float w = (float)__builtin_bit_cast(_Float16, (unsigned short)(vs[j] >> 16));
      float2 tf = __half22float2(tv[j]);
      if (j & 1){ b0 += w * tf.x; b1 += w * tf.y; }
      else      { a0 += w * tf.x; a1 += w * tf.y; }
    }
  }
  a0 += b0; a1 += b1;
  int cc = panel*32 + ql*2;
  a0 = tanh_fast(a0 + bias[cc]);
  a1 = tanh_fast(a1 + bias[cc+1]);
  if (valid)
    *(__half2*)(hp + (size_t)panel*pstride + (size_t)n*32 + ql*2) = __floats2half2_rn(a0, a1);
}

// pool stage 1: 16 blocks/graph, deterministic partial slots (no atomics).
// pmax/psum[(g*16+sub)*128 + col], f32.
__global__ __launch_bounds__(256) void k_pool_part(const _Float16* __restrict__ hp,
                                                   const unsigned* __restrict__ gstart,
                                                   float* __restrict__ pmax,
                                                   float* __restrict__ psum,
                                                   size_t pstride){
  int g = blockIdx.x >> 4, sub = blockIdx.x & 15;
  int tid = threadIdx.x;
  int col = tid & 127, half_ = tid >> 7;
  const _Float16* hpp = hp + (size_t)(col >> 5)*pstride + (col & 31);
  unsigned s0 = gstart[g], s1 = gstart[g+1];
  float m = -INFINITY, sm = 0.f;
  for (unsigned n = s0 + sub*2 + half_; n < s1; n += 32){
    float v = (float)hpp[(size_t)n*32];
    m = fmaxf(m, v); sm += v;
  }
  __shared__ float shm[256], shs[256];
  shm[tid] = m; shs[tid] = sm;
  __syncthreads();
  if (half_ == 0){
    m  = fmaxf(m, shm[tid + 128]);
    sm += shs[tid + 128];
    int slot = (g*16 + sub)*128 + col;
    pmax[slot] = m;
    psum[slot] = sm;
  }
}

// pool stage 2 + head: 64 blocks; reduce 16 partials/col, write hidden, Wout dot
__global__ __launch_bounds__(256) void k_pool_out(const float* __restrict__ pmax,
                                                  const float* __restrict__ psum,
                                                  const unsigned* __restrict__ gstart,
                                                  const float* __restrict__ Wout,
                                                  const float* __restrict__ bout,
                                                  void* __restrict__ outp,
                                                  const int* __restrict__ flags){
  int g = blockIdx.x, tid = threadIdx.x;
  int col = tid & 127, sub = tid >> 7;   // sub 0 -> max half, sub 1 -> mean half
  unsigned cnt = gstart[g+1] - gstart[g];
  float val;
  if (sub == 0){
    float m = -INFINITY;
    #pragma unroll
    for (int j = 0; j < 16; j++) m = fmaxf(m, pmax[(g*16 + j)*128 + col]);
    val = (cnt > 0 && m > -INFINITY) ? m : 0.f;   // empty-graph guard
  } else {
    float s = 0.f;
    #pragma unroll
    for (int j = 0; j < 16; j++) s += psum[(g*16 + j)*128 + col];
    val = s / (float)(cnt ? cnt : 1u);
  }
  int hcol = sub*128 + col;
  int f32out = flags[0];
  int hidx = NGRAPH + g*(2*FDIM) + hcol;
  if (f32out) ((float*)outp)[hidx] = val;
  else        ((bf16*)outp)[hidx] = __float2bfloat16(val);

  __shared__ float red[256];
  red[hcol] = val * Wout[hcol];
  __syncthreads();
  for (int s = 128; s > 0; s >>= 1){
    if (tid < s) red[tid] += red[tid + s];
    __syncthreads();
  }
  if (tid == 0){
    float o = red[0] + bout[0];
    if (f32out) ((float*)outp)[g] = o;
    else        ((bf16*)outp)[g] = __float2bfloat16(o);
  }
}

extern "C" void kernel_launch(void* const* d_in, const int* in_sizes, int n_in,
                              void* d_out, int out_size, void* d_ws, size_t ws_size,
                              hipStream_t stream){
  int N = in_sizes[0] / FDIM;   // x: [N,128]
  int E = in_sizes[3];          // edge_weight: [E]
  int NB = (N + 1023) / 1024;   // scan blocks (<=64 for N<=65536)
  unsigned Epad = (unsigned)E + 8u*(unsigned)N;   // allocation bound for padded CSR
  size_t pstride = (size_t)N * 32;                // fp16 elems per column panel

  char* p = (char*)d_ws;
  auto alloc = [&](size_t bytes){ char* r = p; p += (bytes + 255) & ~(size_t)255; return r; };
  int*       flags  = (int*)      alloc(16);
  float*     pf     = (float*)    alloc((size_t)(66305 + 64)*4);
  _Float16*  wt     = (_Float16*) alloc((size_t)4*FDIM*FDIM*2);
  unsigned long long* packed = (unsigned long long*)alloc((size_t)N*8);
  float*     dinv   = (float*)    alloc((size_t)N*4);
  float*     swv    = (float*)    alloc((size_t)N*4);
  unsigned*  off    = (unsigned*) alloc((size_t)(N+1)*4);
  unsigned*  bsum   = (unsigned*) alloc((size_t)128*4);
  unsigned*  rank   = (unsigned*) alloc((size_t)E*4);
  unsigned*  epk    = (unsigned*) alloc((size_t)Epad*4);
  _Float16*  th     = (_Float16*) alloc((size_t)N*FDIM*2);  // 4 panels
  _Float16*  hh     = (_Float16*) alloc((size_t)N*FDIM*2);  // 4 panels
  float*     pmax   = (float*)    alloc((size_t)NGRAPH*16*128*4);
  float*     psum   = (float*)    alloc((size_t)NGRAPH*16*128*4);
  unsigned*  gstart = (unsigned*) alloc((size_t)(NGRAPH+1)*4);

  float* bf_[4] = {pf + 65536, pf + 65664, pf + 65792, pf + 65920};
  float* Woutf  = pf + 66048;
  float* boutf  = pf + 66304;

  k_probe<<<1, 256, 0, stream>>>((const unsigned short*)d_in[0], (const int*)d_in[1], flags);

  int gE = (E + 255)/256;
  PtrPack pk;
  pk.p[0]=d_in[4]; pk.p[1]=d_in[6]; pk.p[2]=d_in[8]; pk.p[3]=d_in[10];
  pk.p[4]=d_in[5]; pk.p[5]=d_in[7]; pk.p[6]=d_in[9]; pk.p[7]=d_in[11];
  pk.p[8]=d_in[12]; pk.p[9]=d_in[13];
  k_setup<<<(66305 + 255)/256, 256, 0, stream>>>(pk, pf, wt, packed, d_in[2], gstart, N, flags);
  k_edge_deg<<<gE, 256, 0, stream>>>(d_in[1], d_in[3], packed, rank, E, N, flags);
  k_scan_pre<<<NB, 256, 0, stream>>>(packed, dinv, swv, bsum, epk, Epad, N);
  k_scan_mid<<<1, 64, 0, stream>>>(bsum, off, NB, N);
  k_scan_fin<<<NB, 256, 0, stream>>>(packed, bsum, off, N);
  k_bucket<<<gE, 256, 0, stream>>>(d_in[1], d_in[3], dinv, off, rank, epk, E, Epad, N, flags);

  int gG = (N + 63)/64;
  int gA = ((N + 15)/16)*4;     // node-groups(16) x 4 panels

  k_gemm<0><<<gG, 256, 0, stream>>>(d_in[0], wt + 0*16384, th, N, pstride, flags);
  k_agg<<<gA, 256, 0, stream>>>(th, swv, off, epk, bf_[0], hh, N, pstride);
  for (int l = 1; l < 4; l++){
    k_gemm<1><<<gG, 256, 0, stream>>>(hh, wt + (size_t)l*16384, th, N, pstride, flags);
    k_agg<<<gA, 256, 0, stream>>>(th, swv, off, epk, bf_[l], hh, N, pstride);
  }

  k_pool_part<<<16*NGRAPH, 256, 0, stream>>>(hh, gstart, pmax, psum, pstride);
  k_pool_out<<<NGRAPH, 256, 0, stream>>>(pmax, psum, gstart, Woutf, boutf, d_out, flags);
}

// Round 12
// 371.637 us; speedup vs baseline: 1.3337x; 1.0130x over previous
//
#include <hip/hip_runtime.h>
#include <hip/hip_bf16.h>
#include <hip/hip_fp16.h>

typedef __hip_bfloat16 bf16;
typedef _Float16 half8 __attribute__((ext_vector_type(8)));
typedef float f32x4 __attribute__((ext_vector_type(4)));

#define FDIM 128
#define SELF_W 2.0f
#define NGRAPH 64
#define DEG_SCALE 1048576.0f          // 2^20 fixed point for weighted degree
#define DEG_MASK  ((1ull<<44) - 1ull) // low 44 bits = degree sum, high 20 = count

__device__ __forceinline__ float b2f(bf16 v){ return __bfloat162float(v); }

__device__ __forceinline__ float rdf(const void* p, long long i, int f32){
  return f32 ? ((const float*)p)[i] : b2f(((const bf16*)p)[i]);
}
__device__ __forceinline__ int rdi(const void* p, long long i, int i64){
  return i64 ? (int)(((const long long*)p)[i]) : ((const int*)p)[i];
}

// fast tanh: exp+rcp (~8 VALU vs ~30 for libm tanhf); rel err ~2e-7
__device__ __forceinline__ float tanh_fast(float x){
  float ax = fabsf(x);
  float e  = __expf(-2.0f*ax);
  float r  = (1.0f - e) * __builtin_amdgcn_rcpf(1.0f + e);
  return copysignf(r, x);
}

// fused setup: per-block local input-format probe; params -> pf(f32) + WT(fp16,T);
// packed init; graph bounds (tail block); block 0 publishes flags.
struct PtrPack { const void* p[10]; };
__global__ __launch_bounds__(256) void k_setup(PtrPack pk, float* __restrict__ pf,
                                               _Float16* __restrict__ wt,
                                               unsigned long long* __restrict__ packed,
                                               const void* __restrict__ bat,
                                               unsigned* __restrict__ gstart,
                                               const unsigned short* __restrict__ x16,
                                               const int* __restrict__ ei32,
                                               int* __restrict__ flags_out,
                                               int N){
  __shared__ int cbig, codd, sf32, si64;
  int tid = threadIdx.x;
  if (tid == 0){ cbig = 0; codd = 0; }
  __syncthreads();
  for (int i = tid; i < 4096; i += 256){
    int e = (x16[i] >> 7) & 0xFF;
    if (e >= 134) atomicAdd(&cbig, 1);
  }
  for (int i = tid; i < 512; i += 256){
    if (ei32[2*i + 1] != 0) atomicAdd(&codd, 1);
  }
  __syncthreads();
  if (tid == 0){
    sf32 = (cbig >= 64) ? 1 : 0;   // floats are f32
    si64 = (codd < 8)  ? 1 : 0;    // ints are int64
    if (blockIdx.x == 0){ flags_out[0] = sf32; flags_out[1] = si64; }
  }
  __syncthreads();
  int f32 = sf32, i64 = si64;

  const int sz[10]  = {16384,16384,16384,16384,128,128,128,128,256,1};
  const int dst[10] = {0,16384,32768,49152,65536,65664,65792,65920,66048,66304};
  int i = blockIdx.x*blockDim.x + tid;
  if (i < 66305){
    int seg = 0, rem = i;
    while (rem >= sz[seg]){ rem -= sz[seg]; seg++; }
    float v = rdf(pk.p[seg], rem, f32);
    pf[dst[seg] + rem] = v;
    if (seg < 4){                     // W[l][k][n] -> WT[l][n][k] fp16
      int k = rem >> 7, n = rem & 127;
      wt[seg*16384 + n*128 + k] = (_Float16)v;
    }
  }
  // packed degree init (grid-stride)
  int stride = gridDim.x*blockDim.x;
  for (int j = i; j < N; j += stride)
    packed[j] = (unsigned long long)(SELF_W * DEG_SCALE);
  // graph bounds in last block (batch is sorted)
  if (blockIdx.x == gridDim.x - 1){
    __shared__ unsigned s[NGRAPH+1];
    int g = tid;
    if (g <= NGRAPH){
      int lo = 0, hi = N;
      while (lo < hi){ int mid = (lo + hi) >> 1; if (rdi(bat, mid, i64) < g) lo = mid + 1; else hi = mid; }
      s[g] = (unsigned)lo;
    }
    __syncthreads();
    if (g <= NGRAPH) gstart[g] = s[g];
  }
}

// edge pass 1: 2 edges/thread, independent u64 atomics (latency overlap).
// atomic = {count:20 | deg_fixed:44}; returned old -> rank within dst bucket.
__global__ void k_edge_deg(const void* __restrict__ ei, const void* __restrict__ ew,
                           unsigned long long* __restrict__ packed,
                           unsigned* __restrict__ rank,
                           int E, int N, const int* __restrict__ flags){
  int e0 = 2*(blockIdx.x*blockDim.x + threadIdx.x);
  if (e0 >= E) return;
  int i64 = flags[1], f32 = flags[0];
  int e1 = e0 + 1;
  bool h1 = (e1 < E);
  int d0 = rdi(ei, (long long)E + e0, i64);
  int d1 = h1 ? rdi(ei, (long long)E + e1, i64) : 0;
  float w0 = rdf(ew, e0, f32);
  float w1 = h1 ? rdf(ew, e1, f32) : 0.f;
  unsigned r0 = 0u, r1 = 0u;
  if ((unsigned)d0 < (unsigned)N){
    unsigned long long add = (1ull << 44) |
        (unsigned long long)__float2uint_rn(w0 * DEG_SCALE);
    r0 = (unsigned)(atomicAdd(&packed[d0], add) >> 44);
  }
  if (h1 && (unsigned)d1 < (unsigned)N){
    unsigned long long add = (1ull << 44) |
        (unsigned long long)__float2uint_rn(w1 * DEG_SCALE);
    r1 = (unsigned)(atomicAdd(&packed[d1], add) >> 44);
  }
  rank[e0] = r0;
  if (h1) rank[e1] = r1;
}

__device__ __forceinline__ unsigned wave_incl_scan(unsigned v){
  int lane = threadIdx.x & 63;
  #pragma unroll
  for (int d = 1; d < 64; d <<= 1){
    unsigned t = __shfl_up(v, d, 64);
    if (lane >= d) v += t;
  }
  return v;
}

// scan phase A: per-block PADDED-count sum -> bsum; fused dinv + self-weight;
// also prefills epk (grid-stride).
__global__ __launch_bounds__(256) void k_scan_pre(const unsigned long long* __restrict__ packed,
                                                  float* __restrict__ dinv,
                                                  float* __restrict__ swv,
                                                  unsigned* __restrict__ bsum,
                                                  unsigned* __restrict__ epk, unsigned Epad,
                                                  int N){
  __shared__ unsigned wsh[4];
  int tid = threadIdx.x, lane = tid & 63, wid = tid >> 6;
  unsigned gid = blockIdx.x*blockDim.x + tid, gstr = gridDim.x*blockDim.x;
  for (unsigned j = gid; j < Epad; j += gstr) epk[j] = 0u;
  int i0 = blockIdx.x*1024 + tid*4;
  unsigned tsum = 0u;
  #pragma unroll
  for (int j = 0; j < 4; j++){
    int i = i0 + j;
    if (i < N){
      unsigned long long pv = packed[i];
      tsum += ((unsigned)(pv >> 44) + 7u) & ~7u;
      float d = (float)(pv & DEG_MASK) * (1.0f / DEG_SCALE);
      float di = (d > 0.f) ? rsqrtf(d) : 0.f;
      dinv[i] = di;
      swv[i]  = di * di * SELF_W;
    }
  }
  #pragma unroll
  for (int d = 1; d < 64; d <<= 1) tsum += __shfl_down(tsum, d, 64);
  if (lane == 0) wsh[wid] = tsum;
  __syncthreads();
  if (tid == 0) bsum[blockIdx.x] = wsh[0] + wsh[1] + wsh[2] + wsh[3];
}

// scan phase B+C fused: wave 0 re-scans bsum (NB<=64) for this block's base;
// local exclusive scan of padded counts + base -> off; last block writes off[N].
__global__ __launch_bounds__(256) void k_scan_fin(const unsigned long long* __restrict__ packed,
                                                  const unsigned* __restrict__ bsum,
                                                  unsigned* __restrict__ off, int N, int NB){
  __shared__ unsigned wsh[4];
  __shared__ unsigned sbase, stot;
  int tid = threadIdx.x, lane = tid & 63, wid = tid >> 6;
  if (tid < 64){
    unsigned v = (tid < NB) ? bsum[tid] : 0u;
    unsigned isc = wave_incl_scan(v);
    if (tid == (int)blockIdx.x) sbase = isc - v;
    if (tid == 63) stot = isc;
  }
  __syncthreads();
  int i0 = blockIdx.x*1024 + tid*4;
  unsigned v0=0u,v1=0u,v2=0u,v3=0u;
  if (i0+0 < N) v0 = ((unsigned)(packed[i0+0] >> 44) + 7u) & ~7u;
  if (i0+1 < N) v1 = ((unsigned)(packed[i0+1] >> 44) + 7u) & ~7u;
  if (i0+2 < N) v2 = ((unsigned)(packed[i0+2] >> 44) + 7u) & ~7u;
  if (i0+3 < N) v3 = ((unsigned)(packed[i0+3] >> 44) + 7u) & ~7u;
  unsigned tsum = v0+v1+v2+v3;
  unsigned isc = wave_incl_scan(tsum);
  if (lane == 63) wsh[wid] = isc;
  __syncthreads();
  unsigned wbase = 0u;
  #pragma unroll
  for (int w = 0; w < 4; w++) if (w < wid) wbase += wsh[w];
  unsigned ex = sbase + wbase + (isc - tsum);
  if (i0+0 < N) off[i0+0] = ex;
  if (i0+1 < N) off[i0+1] = ex + v0;
  if (i0+2 < N) off[i0+2] = ex + v0 + v1;
  if (i0+3 < N) off[i0+3] = ex + v0 + v1 + v2;
  if (blockIdx.x == gridDim.x - 1 && tid == 0) off[N] = stot;
}

// edge pass 2: 2 edges/thread, ATOMIC-FREE scatter; pack (u16 src | fp16 coef)
__global__ void k_bucket(const void* __restrict__ ei, const void* __restrict__ ew,
                         const float* __restrict__ dinv,
                         const unsigned* __restrict__ off,
                         const unsigned* __restrict__ rank,
                         unsigned* __restrict__ epk,
                         int E, unsigned Epad, int N, const int* __restrict__ flags){
  int e0 = 2*(blockIdx.x*blockDim.x + threadIdx.x);
  if (e0 >= E) return;
  int i64 = flags[1], f32 = flags[0];
  #pragma unroll
  for (int j = 0; j < 2; j++){
    int e = e0 + j;
    if (e >= E) break;
    int s_ = rdi(ei, e, i64);
    int d  = rdi(ei, (long long)E + e, i64);
    if ((unsigned)s_ >= (unsigned)N || (unsigned)d >= (unsigned)N) continue;
    unsigned pos = off[d] + rank[e];
    if (pos < Epad){
      float coef = dinv[s_] * rdf(ew, e, f32) * dinv[d];
      _Float16 ch = (_Float16)coef;
      unsigned cu = (unsigned)__builtin_bit_cast(unsigned short, ch);
      epk[pos] = ((unsigned)s_ & 0xffffu) | (cu << 16);
    }
  }
}

// MFMA GEMM: t(panels) = in[N,128] @ W; fp16 PANEL-layout output [4][N*32].
// MODE 0: in = raw x dense (flag-aware). MODE 1: in = fp16 panels.
template<int MODE>
__global__ __launch_bounds__(256) void k_gemm(const void* __restrict__ in,
                                              const _Float16* __restrict__ WT,
                                              _Float16* __restrict__ outp, int N,
                                              size_t pstride,
                                              const int* __restrict__ flags){
  __shared__ _Float16 sout[4*16*136];   // [wave][16 rows][128+8 cols]
  int tid  = threadIdx.x;
  int wid  = tid >> 6, lane = tid & 63;
  int ln   = lane & 15, quad = lane >> 4;
  int row0 = blockIdx.x * 64;
  int rowA = row0 + wid*16 + ln;
  int rA   = (rowA < N) ? rowA : (N > 0 ? N-1 : 0);

  half8 af[4];
  if (MODE == 1){
    const _Float16* src = (const _Float16*)in;
    #pragma unroll
    for (int kc = 0; kc < 4; kc++)
      af[kc] = *(const half8*)(src + (size_t)kc*pstride + (size_t)rA*32 + quad*8);
  } else {
    if (flags[0]){
      const float* src = (const float*)in + (size_t)rA*FDIM + quad*8;
      #pragma unroll
      for (int kc = 0; kc < 4; kc++){
        float4 a = *(const float4*)(src + kc*32);
        float4 b = *(const float4*)(src + kc*32 + 4);
        half8 h; h[0]=(_Float16)a.x; h[1]=(_Float16)a.y; h[2]=(_Float16)a.z; h[3]=(_Float16)a.w;
        h[4]=(_Float16)b.x; h[5]=(_Float16)b.y; h[6]=(_Float16)b.z; h[7]=(_Float16)b.w;
        af[kc] = h;
      }
    } else {
      const unsigned short* src = (const unsigned short*)in + (size_t)rA*FDIM + quad*8;
      #pragma unroll
      for (int kc = 0; kc < 4; kc++){
        ushort4 u0 = *(const ushort4*)(src + kc*32);
        ushort4 u1 = *(const ushort4*)(src + kc*32 + 4);
        half8 h;
        h[0]=(_Float16)__uint_as_float((unsigned)u0.x<<16);
        h[1]=(_Float16)__uint_as_float((unsigned)u0.y<<16);
        h[2]=(_Float16)__uint_as_float((unsigned)u0.z<<16);
        h[3]=(_Float16)__uint_as_float((unsigned)u0.w<<16);
        h[4]=(_Float16)__uint_as_float((unsigned)u1.x<<16);
        h[5]=(_Float16)__uint_as_float((unsigned)u1.y<<16);
        h[6]=(_Float16)__uint_as_float((unsigned)u1.z<<16);
        h[7]=(_Float16)__uint_as_float((unsigned)u1.w<<16);
        af[kc] = h;
      }
    }
  }

  f32x4 acc[8];
  #pragma unroll
  for (int nt = 0; nt < 8; nt++) acc[nt] = (f32x4){0.f,0.f,0.f,0.f};

  #pragma unroll
  for (int kc = 0; kc < 4; kc++){
    #pragma unroll
    for (int nt = 0; nt < 8; nt++){
      half8 bf = *(const half8*)(WT + (size_t)(nt*16 + ln)*FDIM + kc*32 + quad*8);
      acc[nt] = __builtin_amdgcn_mfma_f32_16x16x32_f16(af[kc], bf, acc[nt], 0, 0, 0);
    }
  }

  _Float16* so = sout + wid*2176;
  #pragma unroll
  for (int nt = 0; nt < 8; nt++)
    #pragma unroll
    for (int reg = 0; reg < 4; reg++)
      so[(quad*4 + reg)*136 + nt*16 + ln] = (_Float16)acc[nt][reg];
  __syncthreads();

  #pragma unroll
  for (int c = 0; c < 4; c++){
    int chunk = tid + c*256;
    int r = chunk >> 4, co = (chunk & 15)*8;
    int row = row0 + r;
    if (row < N){
      half8 v = *(const half8*)(sout + (r>>4)*2176 + (r&15)*136 + co);
      *(half8*)(outp + (size_t)(co>>5)*pstride + (size_t)row*32 + (co & 31)) = v;
    }
  }
}

// panel aggregation: wave = 4 nodes x 1 panel; QUAD = NODE. 16 lanes own one
// half2 column each; walk padded edge list (x8, no tail). Software-pipelined:
// next 8-edge metadata prefetched (clamped addr) before processing current.
__global__ __launch_bounds__(256) void k_agg(const _Float16* __restrict__ tp,
                                             const float* __restrict__ swv,
                                             const unsigned* __restrict__ off,
                                             const unsigned* __restrict__ epk,
                                             const float* __restrict__ bias,
                                             _Float16* __restrict__ hp,
                                             int N, size_t pstride){
  int tid  = threadIdx.x;
  int wv   = tid >> 6, lane = tid & 63;
  int quad = lane >> 4, ql = lane & 15;
  int panel = blockIdx.x & 3;
  int n = (blockIdx.x >> 2)*16 + wv*4 + quad;
  bool valid = (n < N);
  int nn = valid ? n : 0;
  const _Float16* tpp = tp + (size_t)panel*pstride;
  const _Float16* myt = tpp + ql*2;

  float sw = swv[nn];
  float2 sv = __half22float2(*(const __half2*)(myt + (size_t)nn*32));
  float a0 = sw * sv.x, a1 = sw * sv.y;
  float b0 = 0.f, b1 = 0.f;

  unsigned beg = off[nn];
  unsigned end = valid ? off[nn+1] : beg;
  if (beg < end){
    uint4 p0 = *(const uint4*)(epk + beg);
    uint4 p1 = *(const uint4*)(epk + beg + 4);
    for (unsigned i = beg; i < end; i += 8){
      unsigned ni  = i + 8;
      unsigned pre = (ni < end) ? ni : beg;     // clamped prefetch (always valid)
      uint4 q0 = *(const uint4*)(epk + pre);
      uint4 q1 = *(const uint4*)(epk + pre + 4);
      unsigned vs[8] = {p0.x,p0.y,p0.z,p0.w,p1.x,p1.y,p1.z,p1.w};
      __half2 tv[8];
      #pragma unroll
      for (int j = 0; j < 8; j++)
        tv[j] = *(const __half2*)(myt + (size_t)(vs[j] & 0xffffu)*32);
      #pragma unroll
      for (int j = 0; j < 8; j++){
        float w = (float)__builtin_bit_cast(_Float16, (unsigned short)(vs[j] >> 16));
        float2 tf = __half22float2(tv[j]);
        if (j & 1){ b0 += w * tf.x; b1 += w * tf.y; }
        else      { a0 += w * tf.x; a1 += w * tf.y; }
      }
      p0 = q0; p1 = q1;
    }
  }
  a0 += b0; a1 += b1;
  int cc = panel*32 + ql*2;
  a0 = tanh_fast(a0 + bias[cc]);
  a1 = tanh_fast(a1 + bias[cc+1]);
  if (valid)
    *(__half2*)(hp + (size_t)panel*pstride + (size_t)n*32 + ql*2) = __floats2half2_rn(a0, a1);
}

// pool stage 1: 16 blocks/graph, deterministic partial slots (no atomics).
__global__ __launch_bounds__(256) void k_pool_part(const _Float16* __restrict__ hp,
                                                   const unsigned* __restrict__ gstart,
                                                   float* __restrict__ pmax,
                                                   float* __restrict__ psum,
                                                   size_t pstride){
  int g = blockIdx.x >> 4, sub = blockIdx.x & 15;
  int tid = threadIdx.x;
  int col = tid & 127, half_ = tid >> 7;
  const _Float16* hpp = hp + (size_t)(col >> 5)*pstride + (col & 31);
  unsigned s0 = gstart[g], s1 = gstart[g+1];
  float m = -INFINITY, sm = 0.f;
  for (unsigned n = s0 + sub*2 + half_; n < s1; n += 32){
    float v = (float)hpp[(size_t)n*32];
    m = fmaxf(m, v); sm += v;
  }
  __shared__ float shm[256], shs[256];
  shm[tid] = m; shs[tid] = sm;
  __syncthreads();
  if (half_ == 0){
    m  = fmaxf(m, shm[tid + 128]);
    sm += shs[tid + 128];
    int slot = (g*16 + sub)*128 + col;
    pmax[slot] = m;
    psum[slot] = sm;
  }
}

// pool stage 2 + head: 64 blocks; reduce 16 partials/col, write hidden, Wout dot
__global__ __launch_bounds__(256) void k_pool_out(const float* __restrict__ pmax,
                                                  const float* __restrict__ psum,
                                                  const unsigned* __restrict__ gstart,
                                                  const float* __restrict__ Wout,
                                                  const float* __restrict__ bout,
                                                  void* __restrict__ outp,
                                                  const int* __restrict__ flags){
  int g = blockIdx.x, tid = threadIdx.x;
  int col = tid & 127, sub = tid >> 7;   // sub 0 -> max half, sub 1 -> mean half
  unsigned cnt = gstart[g+1] - gstart[g];
  float val;
  if (sub == 0){
    float m = -INFINITY;
    #pragma unroll
    for (int j = 0; j < 16; j++) m = fmaxf(m, pmax[(g*16 + j)*128 + col]);
    val = (cnt > 0 && m > -INFINITY) ? m : 0.f;   // empty-graph guard
  } else {
    float s = 0.f;
    #pragma unroll
    for (int j = 0; j < 16; j++) s += psum[(g*16 + j)*128 + col];
    val = s / (float)(cnt ? cnt : 1u);
  }
  int hcol = sub*128 + col;
  int f32out = flags[0];
  int hidx = NGRAPH + g*(2*FDIM) + hcol;
  if (f32out) ((float*)outp)[hidx] = val;
  else        ((bf16*)outp)[hidx] = __float2bfloat16(val);

  __shared__ float red[256];
  red[hcol] = val * Wout[hcol];
  __syncthreads();
  for (int s = 128; s > 0; s >>= 1){
    if (tid < s) red[tid] += red[tid + s];
    __syncthreads();
  }
  if (tid == 0){
    float o = red[0] + bout[0];
    if (f32out) ((float*)outp)[g] = o;
    else        ((bf16*)outp)[g] = __float2bfloat16(o);
  }
}

extern "C" void kernel_launch(void* const* d_in, const int* in_sizes, int n_in,
                              void* d_out, int out_size, void* d_ws, size_t ws_size,
                              hipStream_t stream){
  int N = in_sizes[0] / FDIM;   // x: [N,128]
  int E = in_sizes[3];          // edge_weight: [E]
  int NB = (N + 1023) / 1024;   // scan blocks (<=64 for N<=65536)
  unsigned Epad = (unsigned)E + 8u*(unsigned)N;   // allocation bound for padded CSR
  size_t pstride = (size_t)N * 32;                // fp16 elems per column panel

  char* p = (char*)d_ws;
  auto alloc = [&](size_t bytes){ char* r = p; p += (bytes + 255) & ~(size_t)255; return r; };
  int*       flags  = (int*)      alloc(16);
  float*     pf     = (float*)    alloc((size_t)(66305 + 64)*4);
  _Float16*  wt     = (_Float16*) alloc((size_t)4*FDIM*FDIM*2);
  unsigned long long* packed = (unsigned long long*)alloc((size_t)N*8);
  float*     dinv   = (float*)    alloc((size_t)N*4);
  float*     swv    = (float*)    alloc((size_t)N*4);
  unsigned*  off    = (unsigned*) alloc((size_t)(N+1)*4);
  unsigned*  bsum   = (unsigned*) alloc((size_t)128*4);
  unsigned*  rank   = (unsigned*) alloc((size_t)E*4);
  unsigned*  epk    = (unsigned*) alloc((size_t)Epad*4);
  _Float16*  th     = (_Float16*) alloc((size_t)N*FDIM*2);  // 4 panels
  _Float16*  hh     = (_Float16*) alloc((size_t)N*FDIM*2);  // 4 panels
  float*     pmax   = (float*)    alloc((size_t)NGRAPH*16*128*4);
  float*     psum   = (float*)    alloc((size_t)NGRAPH*16*128*4);
  unsigned*  gstart = (unsigned*) alloc((size_t)(NGRAPH+1)*4);

  float* bf_[4] = {pf + 65536, pf + 65664, pf + 65792, pf + 65920};
  float* Woutf  = pf + 66048;
  float* boutf  = pf + 66304;

  PtrPack pk;
  pk.p[0]=d_in[4]; pk.p[1]=d_in[6]; pk.p[2]=d_in[8]; pk.p[3]=d_in[10];
  pk.p[4]=d_in[5]; pk.p[5]=d_in[7]; pk.p[6]=d_in[9]; pk.p[7]=d_in[11];
  pk.p[8]=d_in[12]; pk.p[9]=d_in[13];
  k_setup<<<(66305 + 255)/256, 256, 0, stream>>>(pk, pf, wt, packed, d_in[2], gstart,
                                                 (const unsigned short*)d_in[0],
                                                 (const int*)d_in[1], flags, N);
  int gE2 = (E + 511)/512;
  k_edge_deg<<<gE2, 256, 0, stream>>>(d_in[1], d_in[3], packed, rank, E, N, flags);
  k_scan_pre<<<NB, 256, 0, stream>>>(packed, dinv, swv, bsum, epk, Epad, N);
  k_scan_fin<<<NB, 256, 0, stream>>>(packed, bsum, off, N, NB);
  k_bucket<<<gE2, 256, 0, stream>>>(d_in[1], d_in[3], dinv, off, rank, epk, E, Epad, N, flags);

  int gG = (N + 63)/64;
  int gA = ((N + 15)/16)*4;     // node-groups(16) x 4 panels

  k_gemm<0><<<gG, 256, 0, stream>>>(d_in[0], wt + 0*16384, th, N, pstride, flags);
  k_agg<<<gA, 256, 0, stream>>>(th, swv, off, epk, bf_[0], hh, N, pstride);
  for (int l = 1; l < 4; l++){
    k_gemm<1><<<gG, 256, 0, stream>>>(hh, wt + (size_t)l*16384, th, N, pstride, flags);
    k_agg<<<gA, 256, 0, stream>>>(th, swv, off, epk, bf_[l], hh, N, pstride);
  }

  k_pool_part<<<16*NGRAPH, 256, 0, stream>>>(hh, gstart, pmax, psum, pstride);
  k_pool_out<<<NGRAPH, 256, 0, stream>>>(pmax, psum, gstart, Woutf, boutf, d_out, flags);
}